// Round 9
// baseline (64.654 us; speedup 1.0000x reference)
//
#include <hip/hip_runtime.h>
#include <math.h>

#define BB 16
#define NN 8400
#define CC 80
#define MM 64
#define KTOP 13
#define FEPS 1e-9f
#define CAP 2048   // per-(b,m) candidate capacity; theoretical max 1344
#define RPW 8      // u64 regs/lane for selection: RPW*256 == CAP

typedef float floatx4 __attribute__((ext_vector_type(4)));

// ---- output layout (floats) ----
#define OFF_O1 134400
#define OFF_O2 672000
#define OFF_O3 11424000
#define OFF_O4 11558400
// scratch inside cls region tail (all overwritten by k_cls at the end):
// ccnt  [1024 ints]          at CCNT_OFF
// cand  [1024*2048 u16]      at CAND_OFF  (4MB)
// cntb/mselb/aselb [3x134400] at SCR_OFF
#define CCNT_OFF 9299200
#define CAND_OFF 9300224
#define SCR_OFF  10348800

__device__ __forceinline__ float iou_pair(const float4 g, const float4 p) {
    float ix1 = fmaxf(g.x, p.x);
    float iy1 = fmaxf(g.y, p.y);
    float ix2 = fminf(g.z, p.z);
    float iy2 = fminf(g.w, p.w);
    float iw = fmaxf(ix2 - ix1, 0.0f);
    float ih = fmaxf(iy2 - iy1, 0.0f);
    float inter = iw * ih;
    float aa = (g.z - g.x) * (g.w - g.y);
    float ab = (p.z - p.x) * (p.w - p.y);
    float uni = fmaxf(aa + ab - inter, FEPS);
    return inter / uni;
}

// zero ccnt (1024) + cnt/msel/asel (403200) in one launch
__global__ __launch_bounds__(256) void k_zero2(int* __restrict__ ccnt,
                                               int* __restrict__ scr)
{
    int i = blockIdx.x * 256 + threadIdx.x;
    if (i < 1024) ccnt[i] = 0;
    else if (i < 1024 + 403200) scr[i - 1024] = 0;
}

// Phase 1 (dense, full occupancy): each thread = one (b,n) anchor; test against
// all 64 gt boxes (LDS); append hits to per-(b,m) global candidate lists.
__global__ __launch_bounds__(256) void k_inbox(
    const float* __restrict__ anc, const float* __restrict__ gt_bboxes,
    const float* __restrict__ mask_gt,
    int* __restrict__ ccnt, unsigned short* __restrict__ cand)
{
    const int b = blockIdx.y;
    const int n = blockIdx.x * 256 + threadIdx.x;
    const int tid = threadIdx.x;

    __shared__ float4 gtb[MM];
    __shared__ int hcnt[MM];
    __shared__ int gbase[MM];

    if (tid < MM) {
        float4 g = *(const float4*)&gt_bboxes[(size_t)(b * MM + tid) * 4];
        if (mask_gt[b * MM + tid] <= 0.5f)
            g = make_float4(1e30f, 1e30f, -1e30f, -1e30f);  // never hit
        gtb[tid] = g;
        hcnt[tid] = 0;
    }
    __syncthreads();

    float ax = 0.0f, ay = 0.0f;
    const bool inb = n < NN;
    if (inb) { float2 a2 = *(const float2*)&anc[2 * n]; ax = a2.x; ay = a2.y; }

    unsigned long long mask = 0ull;
    #pragma unroll 8
    for (int m = 0; m < MM; ++m) {
        float4 g = gtb[m];
        float d1 = ax - g.x, d2 = ay - g.y, d3 = g.z - ax, d4 = g.w - ay;
        if (inb && fminf(fminf(d1, d2), fminf(d3, d4)) > FEPS)
            mask |= 1ull << m;
    }

    unsigned long long t = mask;
    while (t) { int m = __ffsll(t) - 1; t &= t - 1; atomicAdd(&hcnt[m], 1); }
    __syncthreads();

    if (tid < MM && hcnt[tid] > 0) {
        gbase[tid] = atomicAdd(&ccnt[b * MM + tid], hcnt[tid]);
        hcnt[tid] = 0;
    }
    __syncthreads();

    t = mask;
    while (t) {
        int m = __ffsll(t) - 1; t &= t - 1;
        int slot = gbase[m] + atomicAdd(&hcnt[m], 1);
        if (slot < CAP)
            cand[(size_t)(b * MM + m) * CAP + slot] = (unsigned short)n;
    }
}

// Phase 2: one workgroup per (b,m). Gather scores/boxes for candidates straight
// into registers (8 independent loads in flight per lane), hierarchical
// 4-wave top-13 over unique composites (key<<32)|(NN-n), merge, emit.
__global__ __launch_bounds__(256) void k_topk(
    const float* __restrict__ pd_scores, const float* __restrict__ pd_bboxes,
    const int* __restrict__ gt_labels, const float* __restrict__ gt_bboxes,
    const int* __restrict__ ccnt, const unsigned short* __restrict__ cand,
    int* __restrict__ cntb, int* __restrict__ mselb, float* __restrict__ aselb)
{
    const int bm = blockIdx.x;
    const int b = bm >> 6, m = bm & 63;
    const int tid = threadIdx.x;
    const int lane = tid & 63;
    const int wid = tid >> 6;

    __shared__ unsigned long long cmerge[64];

    const float4 g = *(const float4*)&gt_bboxes[(size_t)bm * 4];
    const int lab  = gt_labels[bm];
    const int labc = lab > 0 ? lab : 0;
    const unsigned epskey = __float_as_uint(FEPS);
    const int count = min(ccnt[bm], CAP);
    const unsigned short* list = cand + (size_t)bm * CAP;
    const float* srow = pd_scores + (size_t)b * NN * CC + labc;
    const float* pbb  = pd_bboxes + (size_t)b * NN * 4;

    // gather + align straight into registers (partition: i = tid + j*256)
    unsigned long long e[RPW];
    #pragma unroll
    for (int j = 0; j < RPW; ++j) {
        int i = tid + j * 256;
        unsigned long long v = 0ull;
        if (i < count) {
            int n = list[i];
            float4 p = *(const float4*)&pbb[(size_t)n * 4];
            float io = iou_pair(g, p);
            float x = srow[(size_t)n * CC];
            float s = 1.0f / (1.0f + expf(-x));
            float i2 = io * io;
            unsigned key = __float_as_uint(s * (i2 * i2 * i2));  // >= 0
            v = ((unsigned long long)key << 32) | (unsigned)(NN - n);
        }
        e[j] = v;
    }

    // stage A: per-wave top-13 of its subset, in registers
    {
        unsigned long long lm = 0ull;
        #pragma unroll
        for (int j = 0; j < RPW; ++j) if (e[j] > lm) lm = e[j];

        unsigned long long winv = 0ull;
        for (int r = 0; r < KTOP; ++r) {
            unsigned long long bv = lm;
            #pragma unroll
            for (int off = 32; off > 0; off >>= 1) {
                unsigned long long ov = __shfl_xor(bv, off, 64);
                if (ov > bv) bv = ov;
            }
            if ((unsigned)(bv >> 32) <= epskey) break;
            if (lane == r) winv = bv;
            if (lm == bv) {                    // unique -> exactly one lane
                #pragma unroll
                for (int j = 0; j < RPW; ++j) if (e[j] == bv) e[j] = 0ull;
                lm = 0ull;
                #pragma unroll
                for (int j = 0; j < RPW; ++j) if (e[j] > lm) lm = e[j];
            }
        }
        if (lane < KTOP) cmerge[wid * KTOP + lane] = winv;
        if (wid == 0 && lane >= 4 * KTOP) cmerge[lane] = 0ull;  // pad 52..63
    }
    __syncthreads();

    // stage B: wave 0 merges 52 candidates -> global top-13, emits positives
    if (wid == 0) {
        unsigned long long v = cmerge[lane];
        unsigned long long winv = 0ull;
        for (int r = 0; r < KTOP; ++r) {
            unsigned long long bv = v;
            #pragma unroll
            for (int off = 32; off > 0; off >>= 1) {
                unsigned long long ov = __shfl_xor(bv, off, 64);
                if (ov > bv) bv = ov;
            }
            if ((unsigned)(bv >> 32) <= epskey) break;
            if (lane == r) winv = bv;
            if (v == bv) v = 0ull;
        }
        if (lane < KTOP) {
            unsigned hk = (unsigned)(winv >> 32);
            if (hk > epskey) {     // positive floats: uint order == float order
                int n = NN - (int)(winv & 0xFFFFFFFFull);
                int ai = b * NN + n;
                atomicAdd(&cntb[ai], 1);
                atomicAdd(&mselb[ai], m);
                atomicAdd(&aselb[ai], __uint_as_float(hk));
            }
        }
    }
}

// Kernel 3: one thread per (b,n). Resolve assignment from scattered positives.
__global__ __launch_bounds__(256) void k_assign(
    const float* __restrict__ pd_scores, const float* __restrict__ pd_bboxes,
    const float* __restrict__ anc, const int* __restrict__ gt_labels,
    const float* __restrict__ gt_bboxes, const float* __restrict__ mask_gt,
    const int* __restrict__ cntb, const int* __restrict__ mselb,
    const float* __restrict__ aselb,
    float* __restrict__ out0, float* __restrict__ out1,
    float* __restrict__ out3, float* __restrict__ out4,
    float* __restrict__ perb)
{
    const int b = blockIdx.y;
    const int n = blockIdx.x * 256 + threadIdx.x;

    __shared__ float4 gtb[MM];
    __shared__ int    labS[MM];
    __shared__ float  mgS[MM];
    if (threadIdx.x < MM) {
        int m = threadIdx.x;
        gtb[m]  = *(const float4*)&gt_bboxes[(size_t)(b * MM + m) * 4];
        labS[m] = gt_labels[b * MM + m];
        mgS[m]  = mask_gt[b * MM + m];
    }
    __syncthreads();
    if (n >= NN) return;

    const size_t idx = (size_t)b * NN + n;
    const int cnt = cntb[idx];

    float per = 0.0f, fg = 0.0f;
    int mstar = 0;

    if (cnt > 0) {
        fg = 1.0f;
        const float4 p = *(const float4*)&pd_bboxes[idx * 4];
        if (cnt == 1) {
            mstar = mselb[idx];
            float a = aselb[idx];
            float io = iou_pair(gtb[mstar], p);   // positive => valid
            per = a / (a + FEPS) * io;
        } else {
            // multi-assigned: reference resolves by argmax IoU over valid m
            float2 a2 = *(const float2*)&anc[2 * n];
            float bestI = -1.0f; int bestM = 0;
            for (int m = 0; m < MM; ++m) {
                float4 gg = gtb[m];
                float d1 = a2.x - gg.x, d2 = a2.y - gg.y;
                float d3 = gg.z - a2.x, d4 = gg.w - a2.y;
                bool valid = (fminf(fminf(d1, d2), fminf(d3, d4)) > FEPS) &&
                             (mgS[m] > 0.5f);
                float io = valid ? iou_pair(gg, p) : 0.0f;
                if (io > bestI) { bestI = io; bestM = m; }   // first-max wins
            }
            mstar = bestM;
            float io = bestI;
            int lb = labS[mstar]; int lbc = lb > 0 ? lb : 0;
            float x = pd_scores[idx * CC + lbc];
            float s = 1.0f / (1.0f + expf(-x));
            float i2 = io * io;
            float a = s * (i2 * i2 * i2);      // continuous-only recompute
            per = a / (a + FEPS) * io;
        }
    }

    out0[idx] = (float)labS[mstar];
    ((float4*)out1)[idx] = gtb[mstar];
    out3[idx] = fg;
    out4[idx] = (float)mstar;
    perb[idx] = per;
}

// Kernel 4: fused zero + one-hot scatter, nontemporal streaming writes.
__global__ __launch_bounds__(256) void k_cls(
    const float* __restrict__ out0, const float* __restrict__ perb,
    floatx4* __restrict__ cls4)
{
    int i = blockIdx.x * 256 + threadIdx.x;      // float4 index, C/4 = 20 per row
    if (i >= BB * NN * CC / 4) return;
    int row = i / 20;
    int c4 = (i - row * 20) * 4;
    int lab = (int)out0[row];
    float per = perb[row];
    int d = lab - c4;
    floatx4 v;
    v.x = (d == 0) ? per : 0.0f;
    v.y = (d == 1) ? per : 0.0f;
    v.z = (d == 2) ? per : 0.0f;
    v.w = (d == 3) ? per : 0.0f;
    __builtin_nontemporal_store(v, &cls4[i]);
}

extern "C" void kernel_launch(void* const* d_in, const int* in_sizes, int n_in,
                              void* d_out, int out_size, void* d_ws, size_t ws_size,
                              hipStream_t stream) {
    const float* pd_scores = (const float*)d_in[0];
    const float* pd_bboxes = (const float*)d_in[1];
    const float* anc       = (const float*)d_in[2];
    const int*   gt_labels = (const int*)d_in[3];
    const float* gt_bboxes = (const float*)d_in[4];
    const float* mask_gt   = (const float*)d_in[5];

    float* out  = (float*)d_out;
    float* out0 = out;
    float* out1 = out + OFF_O1;
    float* out2 = out + OFF_O2;
    float* out3 = out + OFF_O3;
    float* out4 = out + OFF_O4;

    int*            ccnt  = (int*)(out2 + CCNT_OFF);
    unsigned short* cand  = (unsigned short*)(out2 + CAND_OFF);
    float*          scr   = out2 + SCR_OFF;
    int*            cntb  = (int*)scr;
    int*            mselb = (int*)(scr + 134400);
    float*          aselb = scr + 268800;
    float*          perb  = (float*)d_ws;      // B*N floats

    // 0) zero atomic scratch (ccnt + cnt/msel/asel)
    k_zero2<<<dim3((1024 + 403200 + 255) / 256), dim3(256), 0, stream>>>(
        ccnt, (int*)scr);

    // 1) dense in-box test -> per-(b,m) candidate lists (full occupancy)
    k_inbox<<<dim3((NN + 255) / 256, BB), dim3(256), 0, stream>>>(
        anc, gt_bboxes, mask_gt, ccnt, cand);

    // 2) gather + hierarchical register top-13 + emit positives
    k_topk<<<dim3(BB * MM), dim3(256), 0, stream>>>(
        pd_scores, pd_bboxes, gt_labels, gt_bboxes, ccnt, cand,
        cntb, mselb, aselb);

    // 3) per-anchor resolution
    k_assign<<<dim3((NN + 255) / 256, BB), dim3(256), 0, stream>>>(
        pd_scores, pd_bboxes, anc, gt_labels, gt_bboxes, mask_gt,
        cntb, mselb, aselb, out0, out1, out3, out4, perb);

    // 4) cls_targets: fused zero + scatter (nontemporal streaming write)
    const int n4 = (BB * NN * CC) / 4;
    k_cls<<<dim3((n4 + 255) / 256), dim3(256), 0, stream>>>(out0, perb, (floatx4*)out2);
}

// Round 10
// 64.146 us; speedup vs baseline: 1.0079x; 1.0079x over previous
//
#include <hip/hip_runtime.h>
#include <math.h>

#define BB 16
#define NN 8400
#define CC 80
#define MM 64
#define KTOP 13
#define FEPS 1e-9f
#define CAP 2048   // per-(b,m) candidate capacity; theoretical max 1344
#define RPW 8      // u64 regs/lane for selection: RPW*256 == CAP

typedef float floatx4 __attribute__((ext_vector_type(4)));
typedef unsigned long long u64;

// ---- output layout (floats) ----
#define OFF_O1 134400
#define OFF_O2 672000
#define OFF_O3 11424000
#define OFF_O4 11558400
// scratch inside cls region (all overwritten by k_cls at the end):
// ccnt [1024 ints]            at CCNT_OFF
// cand [1024*2048 u64]        at CAND_OFF (16MB)
// cntb/mselb/aselb [3x134400] at SCR_OFF
#define CCNT_OFF 6153472
#define CAND_OFF 6154496
#define SCR_OFF  10348800

__device__ __forceinline__ float iou_pair(const float4 g, const float4 p) {
    float ix1 = fmaxf(g.x, p.x);
    float iy1 = fmaxf(g.y, p.y);
    float ix2 = fminf(g.z, p.z);
    float iy2 = fminf(g.w, p.w);
    float iw = fmaxf(ix2 - ix1, 0.0f);
    float ih = fmaxf(iy2 - iy1, 0.0f);
    float inter = iw * ih;
    float aa = (g.z - g.x) * (g.w - g.y);
    float ab = (p.z - p.x) * (p.w - p.y);
    float uni = fmaxf(aa + ab - inter, FEPS);
    return inter / uni;
}

// zero ccnt (1024) + cnt/msel/asel (403200) in one launch
__global__ __launch_bounds__(256) void k_zero2(int* __restrict__ ccnt,
                                               int* __restrict__ scr)
{
    int i = blockIdx.x * 256 + threadIdx.x;
    if (i < 1024) ccnt[i] = 0;
    else if (i < 1024 + 403200) scr[i - 1024] = 0;
}

// Phase 1 (dense): thread = (b,n) anchor. In-box test vs 64 gt boxes (LDS),
// then for each hit m read the ALIGN inputs from the thread's OWN score row
// (contiguous 320B window per thread -> near-streaming DRAM pattern) and its
// own coalesced pd_bbox; emit u64 composite (key<<32)|(NN-n) to per-(b,m)
// candidate lists via two-level (LDS then global) reservation.
__global__ __launch_bounds__(256) void k_align_emit(
    const float* __restrict__ pd_scores, const float* __restrict__ pd_bboxes,
    const float* __restrict__ anc, const int* __restrict__ gt_labels,
    const float* __restrict__ gt_bboxes, const float* __restrict__ mask_gt,
    int* __restrict__ ccnt, u64* __restrict__ cand)
{
    const int b = blockIdx.y;
    const int n = blockIdx.x * 256 + threadIdx.x;
    const int tid = threadIdx.x;

    __shared__ float4 gtb[MM];
    __shared__ int labS[MM];
    __shared__ int hcnt[MM];
    __shared__ int gbase[MM];

    if (tid < MM) {
        float4 g = *(const float4*)&gt_bboxes[(size_t)(b * MM + tid) * 4];
        if (mask_gt[b * MM + tid] <= 0.5f)
            g = make_float4(1e30f, 1e30f, -1e30f, -1e30f);  // never hit
        gtb[tid] = g;
        int lb = gt_labels[b * MM + tid];
        labS[tid] = lb > 0 ? lb : 0;
        hcnt[tid] = 0;
    }
    __syncthreads();

    float ax = 0.0f, ay = 0.0f;
    const bool inb = n < NN;
    if (inb) { float2 a2 = *(const float2*)&anc[2 * n]; ax = a2.x; ay = a2.y; }

    u64 mask = 0ull;
    #pragma unroll 8
    for (int m = 0; m < MM; ++m) {
        float4 g = gtb[m];
        float d1 = ax - g.x, d2 = ay - g.y, d3 = g.z - ax, d4 = g.w - ay;
        if (inb && fminf(fminf(d1, d2), fminf(d3, d4)) > FEPS)
            mask |= 1ull << m;
    }

    // reserve intra-block slots
    u64 t = mask;
    while (t) { int m = __ffsll(t) - 1; t &= t - 1; atomicAdd(&hcnt[m], 1); }
    __syncthreads();
    if (tid < MM && hcnt[tid] > 0) {
        gbase[tid] = atomicAdd(&ccnt[b * MM + tid], hcnt[tid]);
        hcnt[tid] = 0;
    }
    __syncthreads();

    if (mask) {
        const float4 p = *(const float4*)&pd_bboxes[((size_t)b * NN + n) * 4];
        const float* srow = pd_scores + ((size_t)b * NN + n) * CC;
        t = mask;
        while (t) {
            int m = __ffsll(t) - 1; t &= t - 1;
            float io = iou_pair(gtb[m], p);
            int lab = labS[m];
            float4 c = *(const float4*)(srow + (lab & ~3));   // own-row 16B load
            int r = lab & 3;
            float x = (r == 0) ? c.x : (r == 1) ? c.y : (r == 2) ? c.z : c.w;
            float s = 1.0f / (1.0f + expf(-x));
            float i2 = io * io;
            unsigned key = __float_as_uint(s * (i2 * i2 * i2));  // >= 0
            int slot = gbase[m] + atomicAdd(&hcnt[m], 1);
            if (slot < CAP)
                cand[(size_t)(b * MM + m) * CAP + slot] =
                    ((u64)key << 32) | (unsigned)(NN - n);
        }
    }
}

// Phase 2: one workgroup per (b,m). Coalesced u64 candidate reads straight into
// registers, hierarchical 4-wave top-13 over unique composites, merge, emit.
__global__ __launch_bounds__(256) void k_topk(
    const int* __restrict__ ccnt, const u64* __restrict__ cand,
    int* __restrict__ cntb, int* __restrict__ mselb, float* __restrict__ aselb)
{
    const int bm = blockIdx.x;
    const int b = bm >> 6, m = bm & 63;
    const int tid = threadIdx.x;
    const int lane = tid & 63;
    const int wid = tid >> 6;

    __shared__ u64 cmerge[64];

    const unsigned epskey = __float_as_uint(FEPS);
    const int count = min(ccnt[bm], CAP);
    const u64* list = cand + (size_t)bm * CAP;

    u64 e[RPW];
    #pragma unroll
    for (int j = 0; j < RPW; ++j) {
        int i = tid + j * 256;
        e[j] = (i < count) ? list[i] : 0ull;   // coalesced
    }

    // stage A: per-wave top-13 of its subset, in registers
    {
        u64 lm = 0ull;
        #pragma unroll
        for (int j = 0; j < RPW; ++j) if (e[j] > lm) lm = e[j];

        u64 winv = 0ull;
        for (int r = 0; r < KTOP; ++r) {
            u64 bv = lm;
            #pragma unroll
            for (int off = 32; off > 0; off >>= 1) {
                u64 ov = __shfl_xor(bv, off, 64);
                if (ov > bv) bv = ov;
            }
            if ((unsigned)(bv >> 32) <= epskey) break;
            if (lane == r) winv = bv;
            if (lm == bv) {                    // unique -> exactly one lane
                #pragma unroll
                for (int j = 0; j < RPW; ++j) if (e[j] == bv) e[j] = 0ull;
                lm = 0ull;
                #pragma unroll
                for (int j = 0; j < RPW; ++j) if (e[j] > lm) lm = e[j];
            }
        }
        if (lane < KTOP) cmerge[wid * KTOP + lane] = winv;
        if (wid == 0 && lane >= 4 * KTOP) cmerge[lane] = 0ull;  // pad 52..63
    }
    __syncthreads();

    // stage B: wave 0 merges 52 candidates -> global top-13, emits positives
    if (wid == 0) {
        u64 v = cmerge[lane];
        u64 winv = 0ull;
        for (int r = 0; r < KTOP; ++r) {
            u64 bv = v;
            #pragma unroll
            for (int off = 32; off > 0; off >>= 1) {
                u64 ov = __shfl_xor(bv, off, 64);
                if (ov > bv) bv = ov;
            }
            if ((unsigned)(bv >> 32) <= epskey) break;
            if (lane == r) winv = bv;
            if (v == bv) v = 0ull;
        }
        if (lane < KTOP) {
            unsigned hk = (unsigned)(winv >> 32);
            if (hk > epskey) {     // positive floats: uint order == float order
                int n = NN - (int)(winv & 0xFFFFFFFFull);
                int ai = b * NN + n;
                atomicAdd(&cntb[ai], 1);
                atomicAdd(&mselb[ai], m);
                atomicAdd(&aselb[ai], __uint_as_float(hk));
            }
        }
    }
}

// Kernel 3: one thread per (b,n). Resolve assignment from scattered positives.
__global__ __launch_bounds__(256) void k_assign(
    const float* __restrict__ pd_scores, const float* __restrict__ pd_bboxes,
    const float* __restrict__ anc, const int* __restrict__ gt_labels,
    const float* __restrict__ gt_bboxes, const float* __restrict__ mask_gt,
    const int* __restrict__ cntb, const int* __restrict__ mselb,
    const float* __restrict__ aselb,
    float* __restrict__ out0, float* __restrict__ out1,
    float* __restrict__ out3, float* __restrict__ out4,
    float* __restrict__ perb)
{
    const int b = blockIdx.y;
    const int n = blockIdx.x * 256 + threadIdx.x;

    __shared__ float4 gtb[MM];
    __shared__ int    labS[MM];
    __shared__ float  mgS[MM];
    if (threadIdx.x < MM) {
        int m = threadIdx.x;
        gtb[m]  = *(const float4*)&gt_bboxes[(size_t)(b * MM + m) * 4];
        labS[m] = gt_labels[b * MM + m];
        mgS[m]  = mask_gt[b * MM + m];
    }
    __syncthreads();
    if (n >= NN) return;

    const size_t idx = (size_t)b * NN + n;
    const int cnt = cntb[idx];

    float per = 0.0f, fg = 0.0f;
    int mstar = 0;

    if (cnt > 0) {
        fg = 1.0f;
        const float4 p = *(const float4*)&pd_bboxes[idx * 4];
        if (cnt == 1) {
            mstar = mselb[idx];
            float a = aselb[idx];
            float io = iou_pair(gtb[mstar], p);   // positive => valid
            per = a / (a + FEPS) * io;
        } else {
            // multi-assigned: reference resolves by argmax IoU over valid m
            float2 a2 = *(const float2*)&anc[2 * n];
            float bestI = -1.0f; int bestM = 0;
            for (int m = 0; m < MM; ++m) {
                float4 gg = gtb[m];
                float d1 = a2.x - gg.x, d2 = a2.y - gg.y;
                float d3 = gg.z - a2.x, d4 = gg.w - a2.y;
                bool valid = (fminf(fminf(d1, d2), fminf(d3, d4)) > FEPS) &&
                             (mgS[m] > 0.5f);
                float io = valid ? iou_pair(gg, p) : 0.0f;
                if (io > bestI) { bestI = io; bestM = m; }   // first-max wins
            }
            mstar = bestM;
            float io = bestI;
            int lb = labS[mstar]; int lbc = lb > 0 ? lb : 0;
            float x = pd_scores[idx * CC + lbc];
            float s = 1.0f / (1.0f + expf(-x));
            float i2 = io * io;
            float a = s * (i2 * i2 * i2);      // continuous-only recompute
            per = a / (a + FEPS) * io;
        }
    }

    out0[idx] = (float)labS[mstar];
    ((float4*)out1)[idx] = gtb[mstar];
    out3[idx] = fg;
    out4[idx] = (float)mstar;
    perb[idx] = per;
}

// Kernel 4: fused zero + one-hot scatter, nontemporal streaming writes.
__global__ __launch_bounds__(256) void k_cls(
    const float* __restrict__ out0, const float* __restrict__ perb,
    floatx4* __restrict__ cls4)
{
    int i = blockIdx.x * 256 + threadIdx.x;      // float4 index, C/4 = 20 per row
    if (i >= BB * NN * CC / 4) return;
    int row = i / 20;
    int c4 = (i - row * 20) * 4;
    int lab = (int)out0[row];
    float per = perb[row];
    int d = lab - c4;
    floatx4 v;
    v.x = (d == 0) ? per : 0.0f;
    v.y = (d == 1) ? per : 0.0f;
    v.z = (d == 2) ? per : 0.0f;
    v.w = (d == 3) ? per : 0.0f;
    __builtin_nontemporal_store(v, &cls4[i]);
}

extern "C" void kernel_launch(void* const* d_in, const int* in_sizes, int n_in,
                              void* d_out, int out_size, void* d_ws, size_t ws_size,
                              hipStream_t stream) {
    const float* pd_scores = (const float*)d_in[0];
    const float* pd_bboxes = (const float*)d_in[1];
    const float* anc       = (const float*)d_in[2];
    const int*   gt_labels = (const int*)d_in[3];
    const float* gt_bboxes = (const float*)d_in[4];
    const float* mask_gt   = (const float*)d_in[5];

    float* out  = (float*)d_out;
    float* out0 = out;
    float* out1 = out + OFF_O1;
    float* out2 = out + OFF_O2;
    float* out3 = out + OFF_O3;
    float* out4 = out + OFF_O4;

    int*   ccnt  = (int*)(out2 + CCNT_OFF);
    u64*   cand  = (u64*)(out2 + CAND_OFF);
    float* scr   = out2 + SCR_OFF;
    int*   cntb  = (int*)scr;
    int*   mselb = (int*)(scr + 134400);
    float* aselb = scr + 268800;
    float* perb  = (float*)d_ws;               // B*N floats

    // 0) zero atomic scratch (ccnt + cnt/msel/asel)
    k_zero2<<<dim3((1024 + 403200 + 255) / 256), dim3(256), 0, stream>>>(
        ccnt, (int*)scr);

    // 1) dense in-box + own-row align + emit composites to per-(b,m) lists
    k_align_emit<<<dim3((NN + 255) / 256, BB), dim3(256), 0, stream>>>(
        pd_scores, pd_bboxes, anc, gt_labels, gt_bboxes, mask_gt, ccnt, cand);

    // 2) coalesced hierarchical register top-13 + emit positives
    k_topk<<<dim3(BB * MM), dim3(256), 0, stream>>>(
        ccnt, cand, cntb, mselb, aselb);

    // 3) per-anchor resolution
    k_assign<<<dim3((NN + 255) / 256, BB), dim3(256), 0, stream>>>(
        pd_scores, pd_bboxes, anc, gt_labels, gt_bboxes, mask_gt,
        cntb, mselb, aselb, out0, out1, out3, out4, perb);

    // 4) cls_targets: fused zero + scatter (nontemporal streaming write)
    const int n4 = (BB * NN * CC) / 4;
    k_cls<<<dim3((n4 + 255) / 256), dim3(256), 0, stream>>>(out0, perb, (floatx4*)out2);
}